// Round 3
// baseline (116.620 us; speedup 1.0000x reference)
//
#include <hip/hip_runtime.h>
#include <hip/hip_bf16.h>
#include <math.h>

// Problem constants (match reference setup_inputs)
#define DIMD 128
#define NB    16384        // B  word pairs
#define NK    10           // K  negatives
#define NB2   8192         // B2 mwe batch
#define NL    5            // L  max entity len
#define NW    10           // W  context width
#define NWIN  (NB2 * NW)   // 81920 mwe windows
#define NBLK_W (NB / 4)    // 4096 word blocks (4 waves each)
#define NBLK_M (NWIN / 4)  // 20480 mwe blocks
#define NBLK  (NBLK_W + NBLK_M)

// fast stable softplus: max(z,0) + log(1+exp(-|z|)) via hardware exp2/log2
__device__ __forceinline__ float softplus_fast(float z) {
  return fmaxf(z, 0.0f) + __logf(1.0f + __expf(-fabsf(z)));
}

__device__ __forceinline__ float2 row2(const float* __restrict__ tab, int idx, int lane) {
  return *reinterpret_cast<const float2*>(tab + (size_t)idx * DIMD + 2 * lane);
}

// Reduce-scatter 16 per-lane partials across the wave: lane ends with the full
// 64-lane sum of value idx = 8*b5+4*b4+2*b3+b2 (replicated over the 4 lanes
// sharing bits 5..2). 17 shuffles total.
__device__ __forceinline__ float rs16(float v[16], int lane) {
  const bool b5 = (lane & 32) != 0, b4 = (lane & 16) != 0;
  const bool b3 = (lane & 8) != 0,  b2 = (lane & 4) != 0;
#pragma unroll
  for (int j = 0; j < 8; ++j) {
    float recv = __shfl_xor(b5 ? v[j] : v[j + 8], 32);
    v[j] = (b5 ? v[j + 8] : v[j]) + recv;
  }
#pragma unroll
  for (int j = 0; j < 4; ++j) {
    float recv = __shfl_xor(b4 ? v[j] : v[j + 4], 16);
    v[j] = (b4 ? v[j + 4] : v[j]) + recv;
  }
#pragma unroll
  for (int j = 0; j < 2; ++j) {
    float recv = __shfl_xor(b3 ? v[j] : v[j + 2], 8);
    v[j] = (b3 ? v[j + 2] : v[j]) + recv;
  }
  {
    float recv = __shfl_xor(b2 ? v[0] : v[1], 4);
    v[0] = (b2 ? v[1] : v[0]) + recv;
  }
  float s = v[0];
  s += __shfl_xor(s, 2);
  s += __shfl_xor(s, 1);
  return s;
}

// one window = 1 pos dot + NK neg dots against center vec (cx,cy); returns the
// window's loss term on lanes ≡ 0 (mod 4) slots (others hold 0).
__device__ __forceinline__ float window_term(
    const float* __restrict__ xt, float cx, float cy, int pos,
    const int* __restrict__ nrow, int lane, float zsgn, float wmask) {
  int ni[NK];
#pragma unroll
  for (int k = 0; k < NK; ++k) ni[k] = nrow[k];
  const float2 oe = row2(xt, pos, lane);
  float2 nv[NK];
#pragma unroll
  for (int k = 0; k < NK; ++k) nv[k] = row2(xt, ni[k], lane);

  float v[16];
  v[0] = cx * oe.x + cy * oe.y;
#pragma unroll
  for (int k = 0; k < NK; ++k) v[1 + k] = cx * nv[k].x + cy * nv[k].y;
#pragma unroll
  for (int j = 11; j < 16; ++j) v[j] = 0.0f;

  const float s = rs16(v, lane);
  return softplus_fast(s * zsgn) * wmask;
}

// ---------------- MWE means: one wave per B2 row ----------------
__global__ __launch_bounds__(256) void k_mean(
    const float* __restrict__ ct, const int* __restrict__ mc,
    const int* __restrict__ mlen, float* __restrict__ wsm) {
  const int tid  = blockIdx.x * 256 + threadIdx.x;
  const int g    = tid >> 6;
  const int lane = threadIdx.x & 63;
  const int len  = mlen[g];
  int ti[NL];
#pragma unroll
  for (int t = 0; t < NL; ++t) ti[t] = mc[g * NL + t];
  float mx = 0.0f, my = 0.0f;
#pragma unroll
  for (int t = 0; t < NL; ++t) {
    const float2 e = row2(ct, ti[t], lane);   // unconditional: full ILP
    if (t < len) { mx += e.x; my += e.y; }
  }
  const float inv = 1.0f / (float)len;
  *reinterpret_cast<float2*>(wsm + (size_t)g * DIMD + 2 * lane) =
      make_float2(mx * inv, my * inv);
}

// ---------------- fused main: word pairs + mwe windows, one wave each ----------------
__global__ __launch_bounds__(256) void k_main(
    const float* __restrict__ ct, const float* __restrict__ xt,
    const float* __restrict__ wsm,
    const int* __restrict__ wc, const int* __restrict__ wo,
    const int* __restrict__ wn,
    const int* __restrict__ mo, const int* __restrict__ mn,
    float2* __restrict__ partials) {
  const int bid  = blockIdx.x;
  const int widx = threadIdx.x >> 6;
  const int lane = threadIdx.x & 63;
  const int   idx   = ((lane >> 5) & 1) * 8 + ((lane >> 4) & 1) * 4 +
                      ((lane >> 3) & 1) * 2 + ((lane >> 2) & 1);
  const float zsgn  = (idx == 0) ? -1.0f : 1.0f;
  const float wmask = (((lane & 3) == 0) && idx <= 10) ? 1.0f : 0.0f;

  float term = 0.0f, cnt = 0.0f;
  if (bid < NBLK_W) {
    const int b = bid * 4 + widx;
    const float2 cvec = row2(ct, wc[b], lane);
    term = window_term(xt, cvec.x, cvec.y, wo[b], wn + (size_t)b * NK,
                       lane, zsgn, wmask);
  } else {
    const int win = (bid - NBLK_W) * 4 + widx;
    const int o = mo[win];
    if (o != 0) {                       // wave-uniform: pad window contributes 0
      const int g = win / NW;
      const float2 cvec = row2(wsm, g, lane);
      term = window_term(xt, cvec.x, cvec.y, o, mn + (size_t)win * NK,
                         lane, zsgn, wmask);
      cnt = 1.0f;
    }
  }

  // nonzero terms live only on lanes ≡ 0 (mod 4): coset reduce, total on lane 0
  term += __shfl_xor(term, 4);
  term += __shfl_xor(term, 8);
  term += __shfl_xor(term, 16);
  term += __shfl_xor(term, 32);

  __shared__ float sm[4], sc[4];
  if (lane == 0) { sm[widx] = term; sc[widx] = cnt; }
  __syncthreads();
  if (threadIdx.x == 0)
    partials[bid] = make_float2((sm[0] + sm[1]) + (sm[2] + sm[3]),
                                (sc[0] + sc[1]) + (sc[2] + sc[3]));
}

// ---------------- deterministic final reduction ----------------
__global__ __launch_bounds__(256) void k_final(
    const float2* __restrict__ partials, float* __restrict__ out) {
  __shared__ float sa[256], sb[256], sc[256];
  float S = 0.0f, MS = 0.0f, MC = 0.0f;
  for (int i = threadIdx.x; i < NBLK_W; i += 256) S += partials[i].x;
  for (int i = NBLK_W + threadIdx.x; i < NBLK; i += 256) {
    const float2 v = partials[i];
    MS += v.x; MC += v.y;
  }
  sa[threadIdx.x] = S; sb[threadIdx.x] = MS; sc[threadIdx.x] = MC;
  __syncthreads();
  if (threadIdx.x == 0) {
    float s = 0.0f, ms = 0.0f, mc2 = 0.0f;
    for (int i = 0; i < 256; ++i) { s += sa[i]; ms += sb[i]; mc2 += sc[i]; }
    out[0] = s / (float)NB + 25.0f * (ms / fmaxf(mc2, 1.0f));
  }
}

extern "C" void kernel_launch(void* const* d_in, const int* in_sizes, int n_in,
                              void* d_out, int out_size, void* d_ws, size_t ws_size,
                              hipStream_t stream) {
  const float* ct   = (const float*)d_in[0];  // center_table  (VOCAB, 128)
  const float* xt   = (const float*)d_in[1];  // context_table (VOCAB, 128)
  const int*   wc   = (const int*)d_in[2];
  const int*   wo   = (const int*)d_in[3];
  const int*   wn   = (const int*)d_in[4];
  const int*   mc   = (const int*)d_in[5];
  const int*   mlen = (const int*)d_in[6];
  const int*   mo   = (const int*)d_in[7];
  const int*   mn   = (const int*)d_in[8];

  float*  wsm      = (float*)d_ws;                       // NB2*128 f32 = 4 MB (mwe means)
  float2* partials = (float2*)(wsm + (size_t)NB2 * DIMD); // NBLK float2 = 192 KB

  k_mean<<<NB2 / 4, 256, 0, stream>>>(ct, mc, mlen, wsm);
  k_main<<<NBLK, 256, 0, stream>>>(ct, xt, wsm, wc, wo, wn, mo, mn, partials);
  k_final<<<1, 256, 0, stream>>>(partials, (float*)d_out);
}

// Round 4
// 94.052 us; speedup vs baseline: 1.2399x; 1.2399x over previous
//
#include <hip/hip_runtime.h>
#include <hip/hip_bf16.h>
#include <math.h>

// Problem constants (match reference setup_inputs)
#define DIMD 128
#define NB    16384              // B  word pairs
#define NK    10                 // K  negatives
#define NB2   8192               // B2 mwe batch
#define NL    5                  // L  max entity len
#define NW    10                 // W  context width
#define PPW   4                  // word pairs per wave
#define NBLK_M (NB2 / 4)         // 2048 mwe blocks (1 g per wave, 4 waves/block)
#define NBLK_W (NB / (4 * PPW))  // 1024 word blocks
#define NBLK   (NBLK_M + NBLK_W) // 3072

// fast stable softplus: max(z,0) + log(1+exp(-|z|)), hardware exp/log
__device__ __forceinline__ float softplus_fast(float z) {
  return fmaxf(z, 0.0f) + __logf(1.0f + __expf(-fabsf(z)));
}

__device__ __forceinline__ float4 ld4(const float* __restrict__ p) {
  return *reinterpret_cast<const float4*>(p);
}

// Reduce-scatter 8 per-lane values within each independent 32-lane half
// (all xor distances < 32). Returns the full 32-lane-half sum of value
// idx3 = 4*b4 + 2*b3 + b2 (lane bits), replicated on the 4 lanes sharing
// bits 4..2. 9 shuffles total.
__device__ __forceinline__ float rs8(float v[8], int lane) {
  const bool b4 = (lane & 16) != 0, b3 = (lane & 8) != 0, b2 = (lane & 4) != 0;
#pragma unroll
  for (int j = 0; j < 4; ++j) {
    float recv = __shfl_xor(b4 ? v[j] : v[j + 4], 16);
    v[j] = (b4 ? v[j + 4] : v[j]) + recv;
  }
#pragma unroll
  for (int j = 0; j < 2; ++j) {
    float recv = __shfl_xor(b3 ? v[j] : v[j + 2], 8);
    v[j] = (b3 ? v[j + 2] : v[j]) + recv;
  }
  float recv = __shfl_xor(b2 ? v[0] : v[1], 4);
  float s = (b2 ? v[1] : v[0]) + recv;
  s += __shfl_xor(s, 2);
  s += __shfl_xor(s, 1);
  return s;
}

// One window: softplus terms for dot(center,pos) + 10 dot(center,neg).
// Rows are split half-wave (4 floats/lane, 32 lanes/row); each float4 load
// fetches TWO rows (h=0 row on lanes 0-31, h=1 row on lanes 32-63):
//   slot:  0        1        2        3        4        5
//   h=0:   pos      n1       n3       n5       n7       n9
//   h=1:   n0       n2       n4       n6       n8       n9(dup, masked)
// Result is per-lane masked (nonzero only on lane%4==0, 11 valid cosets).
__device__ __forceinline__ float window_term(
    const float* __restrict__ xtq, float4 c4, int pos,
    const int* __restrict__ nrow, int lane, int h, float zsgn, float wmask) {
  const int2 n01 = *reinterpret_cast<const int2*>(nrow + 0);
  const int2 n23 = *reinterpret_cast<const int2*>(nrow + 2);
  const int2 n45 = *reinterpret_cast<const int2*>(nrow + 4);
  const int2 n67 = *reinterpret_cast<const int2*>(nrow + 6);
  const int2 n89 = *reinterpret_cast<const int2*>(nrow + 8);
  const int i0 = h ? n01.x : pos;
  const int i1 = h ? n23.x : n01.y;
  const int i2 = h ? n45.x : n23.y;
  const int i3 = h ? n67.x : n45.y;
  const int i4 = h ? n89.x : n67.y;
  const int i5 = n89.y;
  const float4 r0 = ld4(xtq + (size_t)i0 * DIMD);
  const float4 r1 = ld4(xtq + (size_t)i1 * DIMD);
  const float4 r2 = ld4(xtq + (size_t)i2 * DIMD);
  const float4 r3 = ld4(xtq + (size_t)i3 * DIMD);
  const float4 r4 = ld4(xtq + (size_t)i4 * DIMD);
  const float4 r5 = ld4(xtq + (size_t)i5 * DIMD);
  float v[8];
  v[0] = c4.x * r0.x + c4.y * r0.y + c4.z * r0.z + c4.w * r0.w;
  v[1] = c4.x * r1.x + c4.y * r1.y + c4.z * r1.z + c4.w * r1.w;
  v[2] = c4.x * r2.x + c4.y * r2.y + c4.z * r2.z + c4.w * r2.w;
  v[3] = c4.x * r3.x + c4.y * r3.y + c4.z * r3.z + c4.w * r3.w;
  v[4] = c4.x * r4.x + c4.y * r4.y + c4.z * r4.z + c4.w * r4.w;
  v[5] = c4.x * r5.x + c4.y * r5.y + c4.z * r5.z + c4.w * r5.w;
  v[6] = 0.0f; v[7] = 0.0f;
  const float s = rs8(v, lane);
  return softplus_fast(s * zsgn) * wmask;
}

// ---------------- fused main: mwe blocks first (longer), then word blocks ----------------
__global__ __launch_bounds__(256) void k_main(
    const float* __restrict__ ct, const float* __restrict__ xt,
    const int* __restrict__ wc, const int* __restrict__ wo,
    const int* __restrict__ wn,
    const int* __restrict__ mc, const int* __restrict__ mlen,
    const int* __restrict__ mo, const int* __restrict__ mn,
    float2* __restrict__ partials) {
  const int bid  = blockIdx.x;
  const int widx = threadIdx.x >> 6;
  const int lane = threadIdx.x & 63;
  const int q = lane & 31, h = lane >> 5;
  const int idx3 = ((lane >> 4) & 1) * 4 + ((lane >> 3) & 1) * 2 + ((lane >> 2) & 1);
  const bool vld = (idx3 < 5) || (idx3 == 5 && h == 0);   // 11 real rows
  const float zsgn  = (idx3 == 0 && h == 0) ? -1.0f : 1.0f;  // pos gets -dot
  const float wmask = (((lane & 3) == 0) && vld) ? 1.0f : 0.0f;
  const float* __restrict__ xtq = xt + q * 4;
  const float* __restrict__ ctq = ct + q * 4;

  float acc = 0.0f, cnt = 0.0f;

  if (bid < NBLK_M) {
    // ---- MWE: one g per wave; mean in registers; 10 windows ----
    const int g = bid * 4 + widx;
    const int len = mlen[g];
    int ti[NL];
#pragma unroll
    for (int t = 0; t < NL; ++t) ti[t] = mc[g * NL + t];
    float4 m = make_float4(0.0f, 0.0f, 0.0f, 0.0f);
#pragma unroll
    for (int t = 0; t < NL; ++t) {
      const float4 e = ld4(ctq + (size_t)ti[t] * DIMD);  // unconditional: ILP
      if (t < len) { m.x += e.x; m.y += e.y; m.z += e.z; m.w += e.w; }
    }
    const float inv = 1.0f / (float)len;
    m.x *= inv; m.y *= inv; m.z *= inv; m.w *= inv;

    int ov[NW];
#pragma unroll
    for (int j = 0; j < NW; j += 2) {
      const int2 o2 = *reinterpret_cast<const int2*>(mo + g * NW + j);
      ov[j] = o2.x; ov[j + 1] = o2.y;
    }
#pragma unroll
    for (int w = 0; w < NW; ++w) {
      const int o = ov[w];
      if (o == 0) continue;          // pad window: vf=0 (wave-uniform)
      acc += window_term(xtq, m, o, mn + (size_t)(g * NW + w) * NK,
                         lane, h, zsgn, wmask);
      cnt += 1.0f;
    }
  } else {
    // ---- words: PPW pairs per wave ----
    const int ww = (bid - NBLK_M) * 4 + widx;
#pragma unroll
    for (int p = 0; p < PPW; ++p) {
      const int b = ww * PPW + p;
      const float4 c4 = ld4(ctq + (size_t)wc[b] * DIMD);
      acc += window_term(xtq, c4, wo[b], wn + (size_t)b * NK,
                         lane, h, zsgn, wmask);
    }
  }

  // window terms live on lanes ≡0 (mod 4); fold the 16 cosets (bits 2..5)
  acc += __shfl_xor(acc, 4);
  acc += __shfl_xor(acc, 8);
  acc += __shfl_xor(acc, 16);
  acc += __shfl_xor(acc, 32);

  __shared__ float sm[4], sc[4];
  if (lane == 0) { sm[widx] = acc; sc[widx] = cnt; }
  __syncthreads();
  if (threadIdx.x == 0)
    partials[bid] = make_float2((sm[0] + sm[1]) + (sm[2] + sm[3]),
                                (sc[0] + sc[1]) + (sc[2] + sc[3]));
}

// ---------------- deterministic final reduction ----------------
__global__ __launch_bounds__(256) void k_final(
    const float2* __restrict__ partials, float* __restrict__ out) {
  __shared__ float sa[256], sb[256], sc[256];
  float S = 0.0f, MS = 0.0f, MC = 0.0f;
  for (int i = threadIdx.x; i < NBLK_M; i += 256) {
    const float2 v = partials[i];
    MS += v.x; MC += v.y;
  }
  for (int i = NBLK_M + threadIdx.x; i < NBLK; i += 256) S += partials[i].x;
  sa[threadIdx.x] = S; sb[threadIdx.x] = MS; sc[threadIdx.x] = MC;
  __syncthreads();
  if (threadIdx.x == 0) {
    float s = 0.0f, ms = 0.0f, mc2 = 0.0f;
    for (int i = 0; i < 256; ++i) { s += sa[i]; ms += sb[i]; mc2 += sc[i]; }
    out[0] = s / (float)NB + 25.0f * (ms / fmaxf(mc2, 1.0f));
  }
}

extern "C" void kernel_launch(void* const* d_in, const int* in_sizes, int n_in,
                              void* d_out, int out_size, void* d_ws, size_t ws_size,
                              hipStream_t stream) {
  const float* ct   = (const float*)d_in[0];  // center_table  (VOCAB, 128)
  const float* xt   = (const float*)d_in[1];  // context_table (VOCAB, 128)
  const int*   wc   = (const int*)d_in[2];
  const int*   wo   = (const int*)d_in[3];
  const int*   wn   = (const int*)d_in[4];
  const int*   mc   = (const int*)d_in[5];
  const int*   mlen = (const int*)d_in[6];
  const int*   mo   = (const int*)d_in[7];
  const int*   mn   = (const int*)d_in[8];

  float2* partials = (float2*)d_ws;   // NBLK float2 = 24 KB

  k_main<<<NBLK, 256, 0, stream>>>(ct, xt, wc, wo, wn, mc, mlen, mo, mn, partials);
  k_final<<<1, 256, 0, stream>>>(partials, (float*)d_out);
}

// Round 5
// 91.238 us; speedup vs baseline: 1.2782x; 1.0308x over previous
//
#include <hip/hip_runtime.h>
#include <hip/hip_bf16.h>
#include <math.h>

// Problem constants (match reference setup_inputs)
#define DIMD 128
#define NB    16384              // B  word pairs
#define NK    10                 // K  negatives
#define NB2   8192               // B2 mwe batch
#define NL    5                  // L  max entity len
#define NW    10                 // W  context width
#define PPW   4                  // word pairs per wave
#define NBLK_M (NB2 / 4)         // 2048 mwe blocks (1 g per wave, 4 waves/block)
#define NBLK_W (NB / (4 * PPW))  // 1024 word blocks
#define NBLK   (NBLK_M + NBLK_W) // 3072

// fast stable softplus: max(z,0) + log(1+exp(-|z|)), hardware exp/log
__device__ __forceinline__ float softplus_fast(float z) {
  return fmaxf(z, 0.0f) + __logf(1.0f + __expf(-fabsf(z)));
}

__device__ __forceinline__ float4 ld4(const float* __restrict__ p) {
  return *reinterpret_cast<const float4*>(p);
}

// Reduce-scatter 8 per-lane values within each independent 32-lane half.
// Lane ends with the 32-half sum of value idx3 = 4*b4+2*b3+b2. 9 shuffles.
__device__ __forceinline__ float rs8(float v[8], int lane) {
  const bool b4 = (lane & 16) != 0, b3 = (lane & 8) != 0, b2 = (lane & 4) != 0;
#pragma unroll
  for (int j = 0; j < 4; ++j) {
    float recv = __shfl_xor(b4 ? v[j] : v[j + 4], 16);
    v[j] = (b4 ? v[j + 4] : v[j]) + recv;
  }
#pragma unroll
  for (int j = 0; j < 2; ++j) {
    float recv = __shfl_xor(b3 ? v[j] : v[j + 2], 8);
    v[j] = (b3 ? v[j + 2] : v[j]) + recv;
  }
  float recv = __shfl_xor(b2 ? v[0] : v[1], 4);
  float s = (b2 ? v[1] : v[0]) + recv;
  s += __shfl_xor(s, 2);
  s += __shfl_xor(s, 1);
  return s;
}

// Issue the 5 index loads + 6 two-row float4 loads for one window.
// Row layout (half-wave rows, 4 floats/lane, 32 lanes/row):
//   slot:  0     1     2     3     4     5
//   h=0:   pos   n1    n3    n5    n7    n9
//   h=1:   n0    n2    n4    n6    n8    n9(dup, masked)
__device__ __forceinline__ void win_issue(
    const float* __restrict__ xtq, int pos, const int* __restrict__ nrow,
    int h, float4 r[6]) {
  const int2 n01 = *reinterpret_cast<const int2*>(nrow + 0);
  const int2 n23 = *reinterpret_cast<const int2*>(nrow + 2);
  const int2 n45 = *reinterpret_cast<const int2*>(nrow + 4);
  const int2 n67 = *reinterpret_cast<const int2*>(nrow + 6);
  const int2 n89 = *reinterpret_cast<const int2*>(nrow + 8);
  const int i0 = h ? n01.x : pos;
  const int i1 = h ? n23.x : n01.y;
  const int i2 = h ? n45.x : n23.y;
  const int i3 = h ? n67.x : n45.y;
  const int i4 = h ? n89.x : n67.y;
  const int i5 = n89.y;
  r[0] = ld4(xtq + (size_t)i0 * DIMD);
  r[1] = ld4(xtq + (size_t)i1 * DIMD);
  r[2] = ld4(xtq + (size_t)i2 * DIMD);
  r[3] = ld4(xtq + (size_t)i3 * DIMD);
  r[4] = ld4(xtq + (size_t)i4 * DIMD);
  r[5] = ld4(xtq + (size_t)i5 * DIMD);
}

__device__ __forceinline__ float win_reduce(
    const float4 r[6], float4 c4, int lane, float zsgn, float wmask) {
  float v[8];
#pragma unroll
  for (int s = 0; s < 6; ++s)
    v[s] = c4.x * r[s].x + c4.y * r[s].y + c4.z * r[s].z + c4.w * r[s].w;
  v[6] = 0.0f; v[7] = 0.0f;
  const float s = rs8(v, lane);
  return softplus_fast(s * zsgn) * wmask;
}

// ---------------- fused main: mwe blocks first (longer), then word blocks ----------------
__global__ __launch_bounds__(256) void k_main(
    const float* __restrict__ ct, const float* __restrict__ xt,
    const int* __restrict__ wc, const int* __restrict__ wo,
    const int* __restrict__ wn,
    const int* __restrict__ mc, const int* __restrict__ mlen,
    const int* __restrict__ mo, const int* __restrict__ mn,
    float2* __restrict__ partials) {
  const int bid  = blockIdx.x;
  const int widx = threadIdx.x >> 6;
  const int lane = threadIdx.x & 63;
  const int q = lane & 31, h = lane >> 5;
  const int idx3 = ((lane >> 4) & 1) * 4 + ((lane >> 3) & 1) * 2 + ((lane >> 2) & 1);
  const bool vld = (idx3 < 5) || (idx3 == 5 && h == 0);       // 11 real rows
  const float zsgn  = (idx3 == 0 && h == 0) ? -1.0f : 1.0f;   // pos gets -dot
  const float wmask = (((lane & 3) == 0) && vld) ? 1.0f : 0.0f;
  const float* __restrict__ xtq = xt + q * 4;
  const float* __restrict__ ctq = ct + q * 4;

  float acc = 0.0f, cnt = 0.0f;

  if (bid < NBLK_M) {
    // ---- MWE: one g per wave; mean in registers; 10 windows, 2 at a time ----
    const int g = bid * 4 + widx;
    const int len = mlen[g];
    int ti[NL];
#pragma unroll
    for (int t = 0; t < NL; ++t) ti[t] = mc[g * NL + t];
    float4 m = make_float4(0.0f, 0.0f, 0.0f, 0.0f);
#pragma unroll
    for (int t = 0; t < NL; ++t) {
      const float4 e = ld4(ctq + (size_t)ti[t] * DIMD);  // unconditional: ILP
      if (t < len) { m.x += e.x; m.y += e.y; m.z += e.z; m.w += e.w; }
    }
    const float inv = 1.0f / (float)len;
    m.x *= inv; m.y *= inv; m.z *= inv; m.w *= inv;

    int ov[NW];
#pragma unroll
    for (int j = 0; j < NW; j += 2) {
      const int2 o2 = *reinterpret_cast<const int2*>(mo + g * NW + j);
      ov[j] = o2.x; ov[j + 1] = o2.y;
    }
    const int* __restrict__ mng = mn + (size_t)g * NW * NK;
#pragma unroll
    for (int w = 0; w < NW; w += 2) {
      const int oa = ov[w], ob = ov[w + 1];
      const float vfa = (oa != 0) ? 1.0f : 0.0f;   // pad (==0) is ~1e-6 rare:
      const float vfb = (ob != 0) ? 1.0f : 0.0f;   // branchless, row 0 load safe
      float4 ra[6], rb[6];
      win_issue(xtq, oa, mng + (size_t)w * NK, h, ra);        // 12 row loads
      win_issue(xtq, ob, mng + (size_t)(w + 1) * NK, h, rb);  // in flight jointly
      const float ta = win_reduce(ra, m, lane, zsgn, wmask);
      const float tb = win_reduce(rb, m, lane, zsgn, wmask);
      acc += ta * vfa + tb * vfb;
      cnt += vfa + vfb;
    }
  } else {
    // ---- words: PPW pairs per wave, 2 at a time ----
    const int ww = (bid - NBLK_M) * 4 + widx;
#pragma unroll
    for (int p = 0; p < PPW; p += 2) {
      const int b0 = ww * PPW + p, b1 = b0 + 1;
      const float4 ca = ld4(ctq + (size_t)wc[b0] * DIMD);
      const float4 cb = ld4(ctq + (size_t)wc[b1] * DIMD);
      float4 ra[6], rb[6];
      win_issue(xtq, wo[b0], wn + (size_t)b0 * NK, h, ra);
      win_issue(xtq, wo[b1], wn + (size_t)b1 * NK, h, rb);
      acc += win_reduce(ra, ca, lane, zsgn, wmask);
      acc += win_reduce(rb, cb, lane, zsgn, wmask);
    }
  }

  // window terms live on lanes ≡0 (mod 4); fold the 16 cosets (bits 2..5)
  acc += __shfl_xor(acc, 4);
  acc += __shfl_xor(acc, 8);
  acc += __shfl_xor(acc, 16);
  acc += __shfl_xor(acc, 32);

  __shared__ float sm[4], sc[4];
  if (lane == 0) { sm[widx] = acc; sc[widx] = cnt; }
  __syncthreads();
  if (threadIdx.x == 0)
    partials[bid] = make_float2((sm[0] + sm[1]) + (sm[2] + sm[3]),
                                (sc[0] + sc[1]) + (sc[2] + sc[3]));
}

// ---------------- deterministic final reduction (tree) ----------------
__global__ __launch_bounds__(256) void k_final(
    const float2* __restrict__ partials, float* __restrict__ out) {
  const int widx = threadIdx.x >> 6, lane = threadIdx.x & 63;
  float S = 0.0f, MS = 0.0f, MC = 0.0f;
  for (int i = threadIdx.x; i < NBLK_M; i += 256) {
    const float2 v = partials[i];
    MS += v.x; MC += v.y;
  }
  for (int i = NBLK_M + threadIdx.x; i < NBLK; i += 256) S += partials[i].x;
#pragma unroll
  for (int d = 32; d >= 1; d >>= 1) {
    S += __shfl_xor(S, d); MS += __shfl_xor(MS, d); MC += __shfl_xor(MC, d);
  }
  __shared__ float sa[4], sb[4], sc[4];
  if (lane == 0) { sa[widx] = S; sb[widx] = MS; sc[widx] = MC; }
  __syncthreads();
  if (threadIdx.x == 0) {
    const float s   = (sa[0] + sa[1]) + (sa[2] + sa[3]);
    const float ms  = (sb[0] + sb[1]) + (sb[2] + sb[3]);
    const float mc2 = (sc[0] + sc[1]) + (sc[2] + sc[3]);
    out[0] = s / (float)NB + 25.0f * (ms / fmaxf(mc2, 1.0f));
  }
}

extern "C" void kernel_launch(void* const* d_in, const int* in_sizes, int n_in,
                              void* d_out, int out_size, void* d_ws, size_t ws_size,
                              hipStream_t stream) {
  const float* ct   = (const float*)d_in[0];  // center_table  (VOCAB, 128)
  const float* xt   = (const float*)d_in[1];  // context_table (VOCAB, 128)
  const int*   wc   = (const int*)d_in[2];
  const int*   wo   = (const int*)d_in[3];
  const int*   wn   = (const int*)d_in[4];
  const int*   mc   = (const int*)d_in[5];
  const int*   mlen = (const int*)d_in[6];
  const int*   mo   = (const int*)d_in[7];
  const int*   mn   = (const int*)d_in[8];

  float2* partials = (float2*)d_ws;   // NBLK float2 = 24 KB

  k_main<<<NBLK, 256, 0, stream>>>(ct, xt, wc, wo, wn, mc, mlen, mo, mn, partials);
  k_final<<<1, 256, 0, stream>>>(partials, (float*)d_out);
}

// Round 7
// 90.473 us; speedup vs baseline: 1.2890x; 1.0085x over previous
//
#include <hip/hip_runtime.h>
#include <hip/hip_bf16.h>
#include <math.h>

// Problem constants (match reference setup_inputs)
#define DIMD 128
#define NB    16384              // B  word pairs
#define NK    10                 // K  negatives
#define NB2   8192               // B2 mwe batch
#define NL    5                  // L  max entity len
#define NW    10                 // W  context width
#define PPW   4                  // word pairs per wave
#define NBLK_M (NB2 / 4)         // 2048 mwe blocks (1 g per wave, 4 waves/block)
#define NBLK_W (NB / (4 * PPW))  // 1024 word blocks
#define NBLK   (NBLK_M + NBLK_W) // 3072

// fast stable softplus: max(z,0) + log(1+exp(-|z|)), hardware exp/log
__device__ __forceinline__ float softplus_fast(float z) {
  return fmaxf(z, 0.0f) + __logf(1.0f + __expf(-fabsf(z)));
}

__device__ __forceinline__ float4 ld4(const float* __restrict__ p) {
  return *reinterpret_cast<const float4*>(p);
}

// Reduce-scatter 8 per-lane values within each independent 32-lane half.
// Lane ends with the 32-half sum of value idx3 = 4*b4+2*b3+b2. 9 shuffles.
__device__ __forceinline__ float rs8(float v[8], int lane) {
  const bool b4 = (lane & 16) != 0, b3 = (lane & 8) != 0, b2 = (lane & 4) != 0;
#pragma unroll
  for (int j = 0; j < 4; ++j) {
    float recv = __shfl_xor(b4 ? v[j] : v[j + 4], 16);
    v[j] = (b4 ? v[j + 4] : v[j]) + recv;
  }
#pragma unroll
  for (int j = 0; j < 2; ++j) {
    float recv = __shfl_xor(b3 ? v[j] : v[j + 2], 8);
    v[j] = (b3 ? v[j + 2] : v[j]) + recv;
  }
  float recv = __shfl_xor(b2 ? v[0] : v[1], 4);
  float s = (b2 ? v[1] : v[0]) + recv;
  s += __shfl_xor(s, 2);
  s += __shfl_xor(s, 1);
  return s;
}

// Issue one window's 5 index loads + 6 two-row float4 loads.
// Row layout (half-wave rows, 4 floats/lane, 32 lanes/row):
//   slot:  0     1     2     3     4     5
//   h=0:   pos   n1    n3    n5    n7    n9
//   h=1:   n0    n2    n4    n6    n8    n9(dup, masked)
#define WIN_ISSUE(R, xtq, pos, nrow, h)                                   \
  do {                                                                    \
    const int2 n01 = *reinterpret_cast<const int2*>((nrow) + 0);          \
    const int2 n23 = *reinterpret_cast<const int2*>((nrow) + 2);          \
    const int2 n45 = *reinterpret_cast<const int2*>((nrow) + 4);          \
    const int2 n67 = *reinterpret_cast<const int2*>((nrow) + 6);          \
    const int2 n89 = *reinterpret_cast<const int2*>((nrow) + 8);          \
    const int i0 = (h) ? n01.x : (pos);                                   \
    const int i1 = (h) ? n23.x : n01.y;                                   \
    const int i2 = (h) ? n45.x : n23.y;                                   \
    const int i3 = (h) ? n67.x : n45.y;                                   \
    const int i4 = (h) ? n89.x : n67.y;                                   \
    const int i5 = n89.y;                                                 \
    R##_0 = ld4((xtq) + (size_t)i0 * DIMD);                               \
    R##_1 = ld4((xtq) + (size_t)i1 * DIMD);                               \
    R##_2 = ld4((xtq) + (size_t)i2 * DIMD);                               \
    R##_3 = ld4((xtq) + (size_t)i3 * DIMD);                               \
    R##_4 = ld4((xtq) + (size_t)i4 * DIMD);                               \
    R##_5 = ld4((xtq) + (size_t)i5 * DIMD);                               \
  } while (0)

#define WIN_REDUCE(out, R, c4, lane, zsgn, wmask)                         \
  do {                                                                    \
    float v[8];                                                           \
    v[0] = (c4).x * R##_0.x + (c4).y * R##_0.y + (c4).z * R##_0.z + (c4).w * R##_0.w; \
    v[1] = (c4).x * R##_1.x + (c4).y * R##_1.y + (c4).z * R##_1.z + (c4).w * R##_1.w; \
    v[2] = (c4).x * R##_2.x + (c4).y * R##_2.y + (c4).z * R##_2.z + (c4).w * R##_2.w; \
    v[3] = (c4).x * R##_3.x + (c4).y * R##_3.y + (c4).z * R##_3.z + (c4).w * R##_3.w; \
    v[4] = (c4).x * R##_4.x + (c4).y * R##_4.y + (c4).z * R##_4.z + (c4).w * R##_4.w; \
    v[5] = (c4).x * R##_5.x + (c4).y * R##_5.y + (c4).z * R##_5.z + (c4).w * R##_5.w; \
    v[6] = 0.0f; v[7] = 0.0f;                                             \
    const float s_ = rs8(v, lane);                                        \
    (out) = softplus_fast(s_ * (zsgn)) * (wmask);                         \
  } while (0)

// ---------------- fused main: mwe blocks first (longer), then word blocks ----------------
__global__ __launch_bounds__(256, 4) void k_main(
    const float* __restrict__ ct, const float* __restrict__ xt,
    const int* __restrict__ wc, const int* __restrict__ wo,
    const int* __restrict__ wn,
    const int* __restrict__ mc, const int* __restrict__ mlen,
    const int* __restrict__ mo, const int* __restrict__ mn,
    float2* __restrict__ partials) {
  const int bid  = blockIdx.x;
  const int widx = threadIdx.x >> 6;
  const int lane = threadIdx.x & 63;
  const int q = lane & 31, h = lane >> 5;
  const int idx3 = ((lane >> 4) & 1) * 4 + ((lane >> 3) & 1) * 2 + ((lane >> 2) & 1);
  const bool vld = (idx3 < 5) || (idx3 == 5 && h == 0);       // 11 real rows
  const float zsgn  = (idx3 == 0 && h == 0) ? -1.0f : 1.0f;   // pos gets -dot
  const float wmask = (((lane & 3) == 0) && vld) ? 1.0f : 0.0f;
  const float* __restrict__ xtq = xt + q * 4;
  const float* __restrict__ ctq = ct + q * 4;

  float acc = 0.0f, cnt = 0.0f;
  float4 A_0, A_1, A_2, A_3, A_4, A_5;   // pipeline buffer A (current window)
  float4 B_0, B_1, B_2, B_3, B_4, B_5;   // pipeline buffer B (next window)

  if (bid < NBLK_M) {
    // ---- MWE: one g per wave; mean in registers; depth-2 pipelined windows ----
    const int g = bid * 4 + widx;
    const int len = mlen[g];
    int ti[NL];
#pragma unroll
    for (int t = 0; t < NL; ++t) ti[t] = mc[g * NL + t];
    // issue mean rows first...
    float4 e0 = ld4(ctq + (size_t)ti[0] * DIMD);
    float4 e1 = ld4(ctq + (size_t)ti[1] * DIMD);
    float4 e2 = ld4(ctq + (size_t)ti[2] * DIMD);
    float4 e3 = ld4(ctq + (size_t)ti[3] * DIMD);
    float4 e4 = ld4(ctq + (size_t)ti[4] * DIMD);

    int ov[NW];
#pragma unroll
    for (int j = 0; j < NW; j += 2) {
      const int2 o2 = *reinterpret_cast<const int2*>(mo + g * NW + j);
      ov[j] = o2.x; ov[j + 1] = o2.y;
    }
    const int* __restrict__ mng = mn + (size_t)g * NW * NK;

    // ...issue window 0 while the mean rows are still in flight...
    WIN_ISSUE(A, xtq, ov[0], mng + 0 * NK, h);

    // ...then finish the mean (waits only the 5 mean rows).
    float4 m = make_float4(0.0f, 0.0f, 0.0f, 0.0f);
    if (0 < len) { m.x += e0.x; m.y += e0.y; m.z += e0.z; m.w += e0.w; }
    if (1 < len) { m.x += e1.x; m.y += e1.y; m.z += e1.z; m.w += e1.w; }
    if (2 < len) { m.x += e2.x; m.y += e2.y; m.z += e2.z; m.w += e2.w; }
    if (3 < len) { m.x += e3.x; m.y += e3.y; m.z += e3.z; m.w += e3.w; }
    if (4 < len) { m.x += e4.x; m.y += e4.y; m.z += e4.z; m.w += e4.w; }
    const float inv = 1.0f / (float)len;
    m.x *= inv; m.y *= inv; m.z *= inv; m.w *= inv;

    float t;
#pragma unroll
    for (int p = 0; p < NW / 2; ++p) {
      const int wA = 2 * p, wB = 2 * p + 1;
      // issue next window BEFORE reducing current one
      WIN_ISSUE(B, xtq, ov[wB], mng + (size_t)wB * NK, h);
      WIN_REDUCE(t, A, m, lane, zsgn, wmask);
      const float vfa = (ov[wA] != 0) ? 1.0f : 0.0f;  // pad is ~1e-6 rare: branchless
      acc += t * vfa; cnt += vfa;
      if (p < NW / 2 - 1)                              // compile-time under unroll
        WIN_ISSUE(A, xtq, ov[wA + 2], mng + (size_t)(wA + 2) * NK, h);
      WIN_REDUCE(t, B, m, lane, zsgn, wmask);
      const float vfb = (ov[wB] != 0) ? 1.0f : 0.0f;
      acc += t * vfb; cnt += vfb;
    }
  } else {
    // ---- words: PPW pairs per wave, depth-2 pipelined ----
    const int ww = (bid - NBLK_M) * 4 + widx;
    const int b0 = ww * PPW;
    int bw[PPW];
#pragma unroll
    for (int p = 0; p < PPW; ++p) bw[p] = wc[b0 + p];
    int po[PPW];
#pragma unroll
    for (int p = 0; p < PPW; ++p) po[p] = wo[b0 + p];

    float4 c0 = ld4(ctq + (size_t)bw[0] * DIMD);
    float4 c1 = ld4(ctq + (size_t)bw[1] * DIMD);
    float4 c2 = ld4(ctq + (size_t)bw[2] * DIMD);
    float4 c3 = ld4(ctq + (size_t)bw[3] * DIMD);

    WIN_ISSUE(A, xtq, po[0], wn + (size_t)(b0 + 0) * NK, h);
    float t;
    WIN_ISSUE(B, xtq, po[1], wn + (size_t)(b0 + 1) * NK, h);
    WIN_REDUCE(t, A, c0, lane, zsgn, wmask); acc += t;
    WIN_ISSUE(A, xtq, po[2], wn + (size_t)(b0 + 2) * NK, h);
    WIN_REDUCE(t, B, c1, lane, zsgn, wmask); acc += t;
    WIN_ISSUE(B, xtq, po[3], wn + (size_t)(b0 + 3) * NK, h);
    WIN_REDUCE(t, A, c2, lane, zsgn, wmask); acc += t;
    WIN_REDUCE(t, B, c3, lane, zsgn, wmask); acc += t;
  }

  // window terms live on lanes ≡0 (mod 4); fold the 16 cosets (bits 2..5)
  acc += __shfl_xor(acc, 4);
  acc += __shfl_xor(acc, 8);
  acc += __shfl_xor(acc, 16);
  acc += __shfl_xor(acc, 32);

  __shared__ float sm[4], sc[4];
  if (lane == 0) { sm[widx] = acc; sc[widx] = cnt; }
  __syncthreads();
  if (threadIdx.x == 0)
    partials[bid] = make_float2((sm[0] + sm[1]) + (sm[2] + sm[3]),
                                (sc[0] + sc[1]) + (sc[2] + sc[3]));
}

// ---------------- deterministic final reduction (tree) ----------------
__global__ __launch_bounds__(256) void k_final(
    const float2* __restrict__ partials, float* __restrict__ out) {
  const int widx = threadIdx.x >> 6, lane = threadIdx.x & 63;
  float S = 0.0f, MS = 0.0f, MC = 0.0f;
  for (int i = threadIdx.x; i < NBLK_M; i += 256) {
    const float2 v = partials[i];
    MS += v.x; MC += v.y;
  }
  for (int i = NBLK_M + threadIdx.x; i < NBLK; i += 256) S += partials[i].x;
#pragma unroll
  for (int d = 32; d >= 1; d >>= 1) {
    S += __shfl_xor(S, d); MS += __shfl_xor(MS, d); MC += __shfl_xor(MC, d);
  }
  __shared__ float sa[4], sb[4], sc[4];
  if (lane == 0) { sa[widx] = S; sb[widx] = MS; sc[widx] = MC; }
  __syncthreads();
  if (threadIdx.x == 0) {
    const float s   = (sa[0] + sa[1]) + (sa[2] + sa[3]);
    const float ms  = (sb[0] + sb[1]) + (sb[2] + sb[3]);
    const float mc2 = (sc[0] + sc[1]) + (sc[2] + sc[3]);
    out[0] = s / (float)NB + 25.0f * (ms / fmaxf(mc2, 1.0f));
  }
}

extern "C" void kernel_launch(void* const* d_in, const int* in_sizes, int n_in,
                              void* d_out, int out_size, void* d_ws, size_t ws_size,
                              hipStream_t stream) {
  const float* ct   = (const float*)d_in[0];  // center_table  (VOCAB, 128)
  const float* xt   = (const float*)d_in[1];  // context_table (VOCAB, 128)
  const int*   wc   = (const int*)d_in[2];
  const int*   wo   = (const int*)d_in[3];
  const int*   wn   = (const int*)d_in[4];
  const int*   mc   = (const int*)d_in[5];
  const int*   mlen = (const int*)d_in[6];
  const int*   mo   = (const int*)d_in[7];
  const int*   mn   = (const int*)d_in[8];

  float2* partials = (float2*)d_ws;   // NBLK float2 = 24 KB

  k_main<<<NBLK, 256, 0, stream>>>(ct, xt, wc, wo, wn, mc, mlen, mo, mn, partials);
  k_final<<<1, 256, 0, stream>>>(partials, (float*)d_out);
}